// Round 6
// baseline (895.603 us; speedup 1.0000x reference)
//
#include <hip/hip_runtime.h>

// Problem constants
constexpr int K    = 512;                 // codebook size
constexpr int CDIM = 64;                  // vector dim
constexpr int NVEC = 8 * 16 * 64 * 64;    // 524288 vectors
constexpr long long NELEM = (long long)NVEC * CDIM; // 33554432

// ws layout (bytes):
//   0    : double sse
//   8    : pad
//   16   : int    counts[512]   (ends 2064)
//   2064 : float  S2[512]
constexpr size_t OFF_SSE    = 0;
constexpr size_t OFF_COUNTS = 16;
constexpr size_t OFF_S2     = 16 + 4 * (size_t)K;

// ---------------------------------------------------------------------------
// S2[k] = np.sum(cb[k]*cb[k]) with numpy pairwise semantics (squares rounded
// first, 8 strided accumulators, fixed combine tree).
__global__ void k_prep(const float* __restrict__ cb, float* __restrict__ S2)
{
#pragma clang fp contract(off)
    int k = threadIdx.x;  // 512 threads, 1 block
    const float* e = cb + (k << 6);
    float sq[CDIM];
    #pragma unroll
    for (int c = 0; c < CDIM; ++c) {
        float v = e[c];
        sq[c] = v * v;                     // rounded square, NO fma
    }
    float r[8];
    #pragma unroll
    for (int j = 0; j < 8; ++j) r[j] = sq[j];
    #pragma unroll
    for (int i = 8; i < CDIM; i += 8)
        #pragma unroll
        for (int j = 0; j < 8; ++j) r[j] += sq[i + j];
    S2[k] = ((r[0] + r[1]) + (r[2] + r[3])) + ((r[4] + r[5]) + (r[6] + r[7]));
}

// ---------------------------------------------------------------------------
// Fused: bit-exact numpy-fp32 argmin + all outputs.
//   D[n,k] = (S1[n] - 2*G[n,k]) + S2[k],  G = sequential-fma dot (BLAS order),
//   idx = first minimum; epilogue does gather/quantize/SSE/histogram.
// Round-4 lesson: the compiler parks f[] in AGPRs regardless (VGPR=44, one
// v_accvgpr_read per use = 2x VALU issue). So pin f to AGPRs EXPLICITLY
// ("+a") and amortize each f-read over 8 codebook fma chains.
__global__ __launch_bounds__(256, 2)
void k_main(const float* __restrict__ x, const float* __restrict__ cb,
            const float* __restrict__ S2g, float* __restrict__ outq,
            float* __restrict__ outidx, double* __restrict__ sse_g,
            int* __restrict__ counts)
{
#pragma clang fp contract(off)
    __shared__ int    hist[K];
    __shared__ double wsum[4];
    const int tid = threadIdx.x;
    for (int i = tid; i < K; i += 256) hist[i] = 0;
    __syncthreads();

    const int n  = blockIdx.x * 256 + tid;
    const int bt = n >> 12;           // (b*16+t)
    const int hw = n & 4095;          // h*64+w
    const size_t base = ((size_t)bt << 18) + (size_t)hw;
    const float* xv = x + base;

    // Load the 64-element vector and pin it in AGPRs (gfx950 unified file):
    // zero memory latency on re-use, and the k8-blocked loop below reads each
    // element only once per 8 codes.
    float f[CDIM];
    #pragma unroll
    for (int c = 0; c < CDIM; ++c) f[c] = xv[(size_t)c << 12];
    #pragma unroll
    for (int c = 0; c < CDIM; ++c) asm volatile("" : "+a"(f[c]));

    // S1 = np pairwise sum of f*f (squares rounded first)
    float r[8];
    #pragma unroll
    for (int j = 0; j < 8; ++j) r[j] = f[j] * f[j];
    #pragma unroll
    for (int i = 8; i < CDIM; i += 8)
        #pragma unroll
        for (int j = 0; j < 8; ++j) r[j] += f[i + j] * f[i + j];
    const float S1 = ((r[0] + r[1]) + (r[2] + r[3])) + ((r[4] + r[5]) + (r[6] + r[7]));

    float best  = 3.4e38f;
    int   bestk = 0;

    // 8 codes per outer iteration: fc read once, 8 sequential-fma chains.
    // e-loads are wave-uniform (k8 uniform) -> scalarized to s_load (SMEM).
    for (int k8 = 0; k8 < K; k8 += 8) {
        const float* eb = cb + (k8 << 6);
        float g[8] = {0.f, 0.f, 0.f, 0.f, 0.f, 0.f, 0.f, 0.f};
        #pragma unroll
        for (int c = 0; c < CDIM; ++c) {
            const float fc = f[c];
            #pragma unroll
            for (int j = 0; j < 8; ++j)
                g[j] = fmaf(fc, eb[j * 64 + c], g[j]);
        }
        // D = (S1 - 2*G) + S2 (2*G exact; adds round at magnitude ~64, exactly
        // like numpy's broadcast expression); first-minimum, ascending k.
        #pragma unroll
        for (int j = 0; j < 8; ++j) {
            const float D = (S1 - 2.f * g[j]) + S2g[k8 + j];
            if (D < best) { best = D; bestk = k8 + j; }
        }
    }

    // ---------------- epilogue ----------------
    atomicAdd(&hist[bestk], 1);
    outidx[n] = (float)bestk;

    const float4* e4 = (const float4*)(cb + (bestk << 6));
    double acc = 0.0;
    #pragma unroll
    for (int c4 = 0; c4 < 16; ++c4) {
        float4 e = e4[c4];
        const int c = c4 * 4;
        float d0 = e.x - f[c + 0];
        float d1 = e.y - f[c + 1];
        float d2 = e.z - f[c + 2];
        float d3 = e.w - f[c + 3];
        outq[base + ((size_t)(c + 0) << 12)] = e.x;
        outq[base + ((size_t)(c + 1) << 12)] = e.y;
        outq[base + ((size_t)(c + 2) << 12)] = e.z;
        outq[base + ((size_t)(c + 3) << 12)] = e.w;
        acc += (double)d0 * d0 + (double)d1 * d1 + (double)d2 * d2 + (double)d3 * d3;
    }

    double v = acc;
    #pragma unroll
    for (int off = 32; off; off >>= 1) v += __shfl_down(v, off, 64);
    if ((tid & 63) == 0) wsum[tid >> 6] = v;
    __syncthreads();
    if (tid == 0) atomicAdd(sse_g, wsum[0] + wsum[1] + wsum[2] + wsum[3]);

    for (int i = tid; i < K; i += 256) {
        int h = hist[i];
        if (h) atomicAdd(&counts[i], h);
    }
}

// ---------------------------------------------------------------------------
// Scalars: vq_loss = 1.25 * SSE / NELEM; entropy in bits from counts.
__global__ void k_final(const double* __restrict__ sse_g, const int* __restrict__ counts,
                        float* __restrict__ out_scalars)
{
    __shared__ double part[8];
    const int t = threadIdx.x;  // 512 threads
    int c = counts[t];
    double p = (double)c / (double)NVEC;
    double h = (c > 0) ? (-p * log2(p)) : 0.0;
    #pragma unroll
    for (int off = 32; off; off >>= 1) h += __shfl_down(h, off, 64);
    if ((t & 63) == 0) part[t >> 6] = h;
    __syncthreads();
    if (t == 0) {
        double H = 0.0;
        #pragma unroll
        for (int i = 0; i < 8; ++i) H += part[i];
        out_scalars[0] = (float)(1.25 * (*sse_g) / (double)NELEM);
        out_scalars[1] = (float)H;
    }
}

// ---------------------------------------------------------------------------
extern "C" void kernel_launch(void* const* d_in, const int* in_sizes, int n_in,
                              void* d_out, int out_size, void* d_ws, size_t ws_size,
                              hipStream_t stream)
{
    const float* x  = (const float*)d_in[0];
    const float* cb = (const float*)d_in[1];

    char* ws = (char*)d_ws;
    double* sse    = (double*)(ws + OFF_SSE);
    int*    counts = (int*)   (ws + OFF_COUNTS);
    float*  S2     = (float*) (ws + OFF_S2);

    float* outq   = (float*)d_out;
    float* outidx = outq + NELEM;
    float* outsc  = outidx + NVEC;

    // zero sse + counts (ws is poisoned 0xAA before every launch)
    hipMemsetAsync(d_ws, 0, OFF_S2, stream);

    k_prep <<<1, 512, 0, stream>>>(cb, S2);
    k_main <<<NVEC / 256, 256, 0, stream>>>(x, cb, S2, outq, outidx, sse, counts);
    k_final<<<1, 512, 0, stream>>>(sse, counts, outsc);
}

// Round 8
// 887.701 us; speedup vs baseline: 1.0089x; 1.0089x over previous
//
#include <hip/hip_runtime.h>

// Problem constants
constexpr int K    = 512;                 // codebook size
constexpr int CDIM = 64;                  // vector dim
constexpr int NVEC = 8 * 16 * 64 * 64;    // 524288 vectors
constexpr long long NELEM = (long long)NVEC * CDIM; // 33554432

// ws layout (bytes):
//   0    : double sse
//   8    : pad
//   16   : int    counts[512]   (ends 2064)
//   2064 : float  S2[512]
constexpr size_t OFF_SSE    = 0;
constexpr size_t OFF_COUNTS = 16;
constexpr size_t OFF_S2     = 16 + 4 * (size_t)K;

// ---------------------------------------------------------------------------
// S2[k] = np.sum(cb[k]*cb[k]) with numpy pairwise semantics (squares rounded
// first, 8 strided accumulators, fixed combine tree).
__global__ void k_prep(const float* __restrict__ cb, float* __restrict__ S2)
{
#pragma clang fp contract(off)
    int k = threadIdx.x;  // 512 threads, 1 block
    const float* e = cb + (k << 6);
    float sq[CDIM];
    #pragma unroll
    for (int c = 0; c < CDIM; ++c) {
        float v = e[c];
        sq[c] = v * v;                     // rounded square, NO fma
    }
    float r[8];
    #pragma unroll
    for (int j = 0; j < 8; ++j) r[j] = sq[j];
    #pragma unroll
    for (int i = 8; i < CDIM; i += 8)
        #pragma unroll
        for (int j = 0; j < 8; ++j) r[j] += sq[i + j];
    S2[k] = ((r[0] + r[1]) + (r[2] + r[3])) + ((r[4] + r[5]) + (r[6] + r[7]));
}

// ---------------------------------------------------------------------------
// Fused: bit-exact numpy-fp32 argmin + all outputs.
//   D[n,k] = (S1[n] - 2*G[n,k]) + S2[k],  G = sequential-fma dot (BLAS order),
//   idx = first minimum; epilogue does gather/quantize/SSE/histogram.
//
// History: r2/r4/r6 all burned ~2.4x the fma issue on per-USE copies of f
// (VMEM reload / v_accvgpr_read rematerialized at every fma). Fix: hoist
// fc once per (c, k8-block) through a VOLATILE empty asm -- cannot be
// duplicated, so the 8 fmas must share the single materialized VGPR.
__global__ __launch_bounds__(256, 4)
void k_main(const float* __restrict__ x, const float* __restrict__ cb,
            const float* __restrict__ S2g, float* __restrict__ outq,
            float* __restrict__ outidx, double* __restrict__ sse_g,
            int* __restrict__ counts)
{
#pragma clang fp contract(off)
    __shared__ int    hist[K];
    __shared__ double wsum[4];
    const int tid = threadIdx.x;
    for (int i = tid; i < K; i += 256) hist[i] = 0;
    __syncthreads();

    const int n  = blockIdx.x * 256 + tid;
    const int bt = n >> 12;           // (b*16+t)
    const int hw = n & 4095;          // h*64+w
    const size_t base = ((size_t)bt << 18) + (size_t)hw;
    const float* xv = x + base;

    // Load the 64-element vector; ask for VGPR homes (non-binding if the
    // allocator prefers AGPR -- the per-block fc pin below caps the cost).
    float f[CDIM];
    #pragma unroll
    for (int c = 0; c < CDIM; ++c) f[c] = xv[(size_t)c << 12];
    #pragma unroll
    for (int c = 0; c < CDIM; ++c) asm volatile("" : "+v"(f[c]));

    // S1 = np pairwise sum of f*f (squares rounded first)
    float r[8];
    #pragma unroll
    for (int j = 0; j < 8; ++j) r[j] = f[j] * f[j];
    #pragma unroll
    for (int i = 8; i < CDIM; i += 8)
        #pragma unroll
        for (int j = 0; j < 8; ++j) r[j] += f[i + j] * f[i + j];
    const float S1 = ((r[0] + r[1]) + (r[2] + r[3])) + ((r[4] + r[5]) + (r[6] + r[7]));

    float best  = 3.4e38f;
    int   bestk = 0;

    // 8 codes per outer iteration: fc materialized ONCE (volatile pin),
    // 8 sequential-fma chains read it. e-loads are wave-uniform -> SMEM.
    for (int k8 = 0; k8 < K; k8 += 8) {
        const float* eb = cb + (k8 << 6);
        float g[8] = {0.f, 0.f, 0.f, 0.f, 0.f, 0.f, 0.f, 0.f};
        #pragma unroll
        for (int c = 0; c < CDIM; ++c) {
            float fc = f[c];
            asm volatile("" : "+v"(fc));   // un-duplicable: one copy per (c,k8)
            #pragma unroll
            for (int j = 0; j < 8; ++j)
                g[j] = fmaf(fc, eb[j * 64 + c], g[j]);
        }
        // D = (S1 - 2*G) + S2 (2*G exact; adds round at magnitude ~64, exactly
        // like numpy's broadcast expression); first-minimum, ascending k.
        #pragma unroll
        for (int j = 0; j < 8; ++j) {
            const float D = (S1 - 2.f * g[j]) + S2g[k8 + j];
            if (D < best) { best = D; bestk = k8 + j; }
        }
    }

    // ---------------- epilogue ----------------
    atomicAdd(&hist[bestk], 1);
    outidx[n] = (float)bestk;

    const float4* e4 = (const float4*)(cb + (bestk << 6));
    double acc = 0.0;
    #pragma unroll
    for (int c4 = 0; c4 < 16; ++c4) {
        float4 e = e4[c4];
        const int c = c4 * 4;
        float d0 = e.x - f[c + 0];
        float d1 = e.y - f[c + 1];
        float d2 = e.z - f[c + 2];
        float d3 = e.w - f[c + 3];
        outq[base + ((size_t)(c + 0) << 12)] = e.x;
        outq[base + ((size_t)(c + 1) << 12)] = e.y;
        outq[base + ((size_t)(c + 2) << 12)] = e.z;
        outq[base + ((size_t)(c + 3) << 12)] = e.w;
        acc += (double)d0 * d0 + (double)d1 * d1 + (double)d2 * d2 + (double)d3 * d3;
    }

    double v = acc;
    #pragma unroll
    for (int off = 32; off; off >>= 1) v += __shfl_down(v, off, 64);
    if ((tid & 63) == 0) wsum[tid >> 6] = v;
    __syncthreads();
    if (tid == 0) atomicAdd(sse_g, wsum[0] + wsum[1] + wsum[2] + wsum[3]);

    for (int i = tid; i < K; i += 256) {
        int h = hist[i];
        if (h) atomicAdd(&counts[i], h);
    }
}

// ---------------------------------------------------------------------------
// Scalars: vq_loss = 1.25 * SSE / NELEM; entropy in bits from counts.
__global__ void k_final(const double* __restrict__ sse_g, const int* __restrict__ counts,
                        float* __restrict__ out_scalars)
{
    __shared__ double part[8];
    const int t = threadIdx.x;  // 512 threads
    int c = counts[t];
    double p = (double)c / (double)NVEC;
    double h = (c > 0) ? (-p * log2(p)) : 0.0;
    #pragma unroll
    for (int off = 32; off; off >>= 1) h += __shfl_down(h, off, 64);
    if ((t & 63) == 0) part[t >> 6] = h;
    __syncthreads();
    if (t == 0) {
        double H = 0.0;
        #pragma unroll
        for (int i = 0; i < 8; ++i) H += part[i];
        out_scalars[0] = (float)(1.25 * (*sse_g) / (double)NELEM);
        out_scalars[1] = (float)H;
    }
}

// ---------------------------------------------------------------------------
extern "C" void kernel_launch(void* const* d_in, const int* in_sizes, int n_in,
                              void* d_out, int out_size, void* d_ws, size_t ws_size,
                              hipStream_t stream)
{
    const float* x  = (const float*)d_in[0];
    const float* cb = (const float*)d_in[1];

    char* ws = (char*)d_ws;
    double* sse    = (double*)(ws + OFF_SSE);
    int*    counts = (int*)   (ws + OFF_COUNTS);
    float*  S2     = (float*) (ws + OFF_S2);

    float* outq   = (float*)d_out;
    float* outidx = outq + NELEM;
    float* outsc  = outidx + NVEC;

    // zero sse + counts (ws is poisoned 0xAA before every launch)
    hipMemsetAsync(d_ws, 0, OFF_S2, stream);

    k_prep <<<1, 512, 0, stream>>>(cb, S2);
    k_main <<<NVEC / 256, 256, 0, stream>>>(x, cb, S2, outq, outidx, sse, counts);
    k_final<<<1, 512, 0, stream>>>(sse, counts, outsc);
}

// Round 9
// 818.581 us; speedup vs baseline: 1.0941x; 1.0844x over previous
//
#include <hip/hip_runtime.h>

// Problem constants
constexpr int K    = 512;                 // codebook size
constexpr int CDIM = 64;                  // vector dim
constexpr int NVEC = 8 * 16 * 64 * 64;    // 524288 vectors
constexpr long long NELEM = (long long)NVEC * CDIM; // 33554432

// ws layout (bytes):
//   0    : double sse
//   8    : pad
//   16   : int    counts[512]   (ends 2064)
//   2064 : float  S2[512]
constexpr size_t OFF_SSE    = 0;
constexpr size_t OFF_COUNTS = 16;
constexpr size_t OFF_S2     = 16 + 4 * (size_t)K;

// ---------------------------------------------------------------------------
// S2[k] = np.sum(cb[k]*cb[k]) with numpy pairwise semantics (squares rounded
// first, 8 strided accumulators, fixed combine tree).
__global__ void k_prep(const float* __restrict__ cb, float* __restrict__ S2)
{
#pragma clang fp contract(off)
    int k = threadIdx.x;  // 512 threads, 1 block
    const float* e = cb + (k << 6);
    float sq[CDIM];
    #pragma unroll
    for (int c = 0; c < CDIM; ++c) {
        float v = e[c];
        sq[c] = v * v;                     // rounded square, NO fma
    }
    float r[8];
    #pragma unroll
    for (int j = 0; j < 8; ++j) r[j] = sq[j];
    #pragma unroll
    for (int i = 8; i < CDIM; i += 8)
        #pragma unroll
        for (int j = 0; j < 8; ++j) r[j] += sq[i + j];
    S2[k] = ((r[0] + r[1]) + (r[2] + r[3])) + ((r[4] + r[5]) + (r[6] + r[7]));
}

// ---------------------------------------------------------------------------
// Fused: bit-exact numpy-fp32 argmin + all outputs.
//   D[n,k] = (S1[n] - 2*G[n,k]) + S2[k],  G = sequential-fma dot (BLAS order),
//   idx = first minimum; epilogue does gather/quantize/SSE/histogram.
//
// r2/r4/r6/r8 lesson: the compiler SINKS the 64 x-loads into the k-loop
// (one reload/copy per fma use, ~2.4x the fma issue) -- legal only because
// x's memory is provably unmodified. The never-taken fake store through an
// x-derived pointer below removes that legality: after it, f cannot be
// re-loaded, so all 64 values must stay register-resident. No asm pins
// (r8 showed they break e-load scalarization: SGPR 112 -> 48).
__global__ __launch_bounds__(256, 3)
void k_main(const float* __restrict__ x, const float* __restrict__ cb,
            const float* __restrict__ S2g, float* __restrict__ outq,
            float* __restrict__ outidx, double* __restrict__ sse_g,
            int* __restrict__ counts)
{
#pragma clang fp contract(off)
    __shared__ int    hist[K];
    __shared__ double wsum[4];
    const int tid = threadIdx.x;
    for (int i = tid; i < K; i += 256) hist[i] = 0;
    __syncthreads();

    const int n  = blockIdx.x * 256 + tid;
    const int bt = n >> 12;           // (b*16+t)
    const int hw = n & 4095;          // h*64+w
    const size_t base = ((size_t)bt << 18) + (size_t)hw;
    const float* xv = x + base;

    // Load the 64-element vector (coalesced across lanes for each c).
    float f[CDIM];
    #pragma unroll
    for (int c = 0; c < CDIM; ++c) f[c] = xv[(size_t)c << 12];

    // S1 = np pairwise sum of f*f (squares rounded first)
    float r[8];
    #pragma unroll
    for (int j = 0; j < 8; ++j) r[j] = f[j] * f[j];
    #pragma unroll
    for (int i = 8; i < CDIM; i += 8)
        #pragma unroll
        for (int j = 0; j < 8; ++j) r[j] += f[i + j] * f[i + j];
    const float S1 = ((r[0] + r[1]) + (r[2] + r[3])) + ((r[4] + r[5]) + (r[6] + r[7]));

    // ---- THE FENCE: never executes (n >= 0 at runtime), but the compiler
    // cannot prove n != -1, so x's memory is potentially clobbered here.
    // Re-loading f[] below this point would be illegal -> f stays in VGPRs.
    if (n == -1) const_cast<float*>(x)[0] = 0.f;

    float best  = 3.4e38f;
    int   bestk = 0;

    for (int k = 0; k < K; k += 4) {
        const float4* e0 = (const float4*)(cb + ((k + 0) << 6));
        const float4* e1 = (const float4*)(cb + ((k + 1) << 6));
        const float4* e2 = (const float4*)(cb + ((k + 2) << 6));
        const float4* e3 = (const float4*)(cb + ((k + 3) << 6));
        float g0 = 0.f, g1 = 0.f, g2 = 0.f, g3 = 0.f;
        #pragma unroll
        for (int c4 = 0; c4 < 16; ++c4) {
            const int c = c4 * 4;
            float4 a = e0[c4];
            g0 = fmaf(f[c + 0], a.x, g0); g0 = fmaf(f[c + 1], a.y, g0);
            g0 = fmaf(f[c + 2], a.z, g0); g0 = fmaf(f[c + 3], a.w, g0);
            float4 b = e1[c4];
            g1 = fmaf(f[c + 0], b.x, g1); g1 = fmaf(f[c + 1], b.y, g1);
            g1 = fmaf(f[c + 2], b.z, g1); g1 = fmaf(f[c + 3], b.w, g1);
            float4 cc = e2[c4];
            g2 = fmaf(f[c + 0], cc.x, g2); g2 = fmaf(f[c + 1], cc.y, g2);
            g2 = fmaf(f[c + 2], cc.z, g2); g2 = fmaf(f[c + 3], cc.w, g2);
            float4 d = e3[c4];
            g3 = fmaf(f[c + 0], d.x, g3); g3 = fmaf(f[c + 1], d.y, g3);
            g3 = fmaf(f[c + 2], d.z, g3); g3 = fmaf(f[c + 3], d.w, g3);
        }
        // D = (S1 - 2*G) + S2   (2*G exact; adds round at magnitude ~64,
        // exactly like numpy's broadcast expression)
        const float d0 = (S1 - 2.f * g0) + S2g[k + 0];
        const float d1 = (S1 - 2.f * g1) + S2g[k + 1];
        const float d2 = (S1 - 2.f * g2) + S2g[k + 2];
        const float d3 = (S1 - 2.f * g3) + S2g[k + 3];
        // first-minimum selection, ascending k
        if (d0 < best) { best = d0; bestk = k + 0; }
        if (d1 < best) { best = d1; bestk = k + 1; }
        if (d2 < best) { best = d2; bestk = k + 2; }
        if (d3 < best) { best = d3; bestk = k + 3; }
    }

    // ---------------- epilogue ----------------
    atomicAdd(&hist[bestk], 1);
    outidx[n] = (float)bestk;

    const float4* e4 = (const float4*)(cb + (bestk << 6));
    double acc = 0.0;
    #pragma unroll
    for (int c4 = 0; c4 < 16; ++c4) {
        float4 e = e4[c4];
        const int c = c4 * 4;
        float d0 = e.x - f[c + 0];
        float d1 = e.y - f[c + 1];
        float d2 = e.z - f[c + 2];
        float d3 = e.w - f[c + 3];
        outq[base + ((size_t)(c + 0) << 12)] = e.x;
        outq[base + ((size_t)(c + 1) << 12)] = e.y;
        outq[base + ((size_t)(c + 2) << 12)] = e.z;
        outq[base + ((size_t)(c + 3) << 12)] = e.w;
        acc += (double)d0 * d0 + (double)d1 * d1 + (double)d2 * d2 + (double)d3 * d3;
    }

    double v = acc;
    #pragma unroll
    for (int off = 32; off; off >>= 1) v += __shfl_down(v, off, 64);
    if ((tid & 63) == 0) wsum[tid >> 6] = v;
    __syncthreads();
    if (tid == 0) atomicAdd(sse_g, wsum[0] + wsum[1] + wsum[2] + wsum[3]);

    for (int i = tid; i < K; i += 256) {
        int h = hist[i];
        if (h) atomicAdd(&counts[i], h);
    }
}

// ---------------------------------------------------------------------------
// Scalars: vq_loss = 1.25 * SSE / NELEM; entropy in bits from counts.
__global__ void k_final(const double* __restrict__ sse_g, const int* __restrict__ counts,
                        float* __restrict__ out_scalars)
{
    __shared__ double part[8];
    const int t = threadIdx.x;  // 512 threads
    int c = counts[t];
    double p = (double)c / (double)NVEC;
    double h = (c > 0) ? (-p * log2(p)) : 0.0;
    #pragma unroll
    for (int off = 32; off; off >>= 1) h += __shfl_down(h, off, 64);
    if ((t & 63) == 0) part[t >> 6] = h;
    __syncthreads();
    if (t == 0) {
        double H = 0.0;
        #pragma unroll
        for (int i = 0; i < 8; ++i) H += part[i];
        out_scalars[0] = (float)(1.25 * (*sse_g) / (double)NELEM);
        out_scalars[1] = (float)H;
    }
}

// ---------------------------------------------------------------------------
extern "C" void kernel_launch(void* const* d_in, const int* in_sizes, int n_in,
                              void* d_out, int out_size, void* d_ws, size_t ws_size,
                              hipStream_t stream)
{
    const float* x  = (const float*)d_in[0];
    const float* cb = (const float*)d_in[1];

    char* ws = (char*)d_ws;
    double* sse    = (double*)(ws + OFF_SSE);
    int*    counts = (int*)   (ws + OFF_COUNTS);
    float*  S2     = (float*) (ws + OFF_S2);

    float* outq   = (float*)d_out;
    float* outidx = outq + NELEM;
    float* outsc  = outidx + NVEC;

    // zero sse + counts (ws is poisoned 0xAA before every launch)
    hipMemsetAsync(d_ws, 0, OFF_S2, stream);

    k_prep <<<1, 512, 0, stream>>>(cb, S2);
    k_main <<<NVEC / 256, 256, 0, stream>>>(x, cb, S2, outq, outidx, sse, counts);
    k_final<<<1, 512, 0, stream>>>(sse, counts, outsc);
}

// Round 11
// 745.096 us; speedup vs baseline: 1.2020x; 1.0986x over previous
//
#include <hip/hip_runtime.h>

// Problem constants
constexpr int K    = 512;                 // codebook size
constexpr int CDIM = 64;                  // vector dim
constexpr int NVEC = 8 * 16 * 64 * 64;    // 524288 vectors
constexpr long long NELEM = (long long)NVEC * CDIM; // 33554432

// ws layout (bytes):
//   0    : double sse
//   8    : pad
//   16   : int    counts[512]   (ends 2064)
//   2064 : float  S2[512]
constexpr size_t OFF_SSE    = 0;
constexpr size_t OFF_COUNTS = 16;
constexpr size_t OFF_S2     = 16 + 4 * (size_t)K;

// ---------------------------------------------------------------------------
// S2[k] = np.sum(cb[k]*cb[k]) with numpy pairwise semantics (squares rounded
// first, 8 strided accumulators, fixed combine tree).
__global__ void k_prep(const float* __restrict__ cb, float* __restrict__ S2)
{
#pragma clang fp contract(off)
    int k = threadIdx.x;  // 512 threads, 1 block
    const float* e = cb + (k << 6);
    float sq[CDIM];
    #pragma unroll
    for (int c = 0; c < CDIM; ++c) {
        float v = e[c];
        sq[c] = v * v;                     // rounded square, NO fma
    }
    float r[8];
    #pragma unroll
    for (int j = 0; j < 8; ++j) r[j] = sq[j];
    #pragma unroll
    for (int i = 8; i < CDIM; i += 8)
        #pragma unroll
        for (int j = 0; j < 8; ++j) r[j] += sq[i + j];
    S2[k] = ((r[0] + r[1]) + (r[2] + r[3])) + ((r[4] + r[5]) + (r[6] + r[7]));
}

// ---------------------------------------------------------------------------
// Fused: bit-exact numpy-fp32 argmin + all outputs.
//   D[n,k] = (S1[n] - 2*G[n,k]) + S2[k],  G = sequential-fma dot (BLAS order),
//   idx = first minimum; epilogue does gather/quantize/SSE/histogram.
//
// r2..r9 lesson: whatever the source says, the allocator parks f[64] in
// AGPRs and REMATERIALIZES one v_accvgpr_read per fma use (~32k extra VALU
// ops, 2.4x the fma issue; busy-equiv constant ~520-577us across four
// structures). LLVM cannot duplicate an inline-asm block, so the 8-fma asm
// below forces ONE fc materialization per 8 codes (4096 copies total) and
// keeps the 8 accumulators in arch VGPRs. Non-volatile, pure dataflow:
// e-loads stay scalarized (s_load, SGPR~112 -- r8 showed volatile asm
// breaks this). v_fmac_f32 g,e,fc == g = fmaf(fc,e,g), IEEE RTNE, and each
// code's chain still ascends c=0..63 -> bit-exact vs all passing rounds.
__global__ __launch_bounds__(256, 4)
void k_main(const float* __restrict__ x, const float* __restrict__ cb,
            const float* __restrict__ S2g, float* __restrict__ outq,
            float* __restrict__ outidx, double* __restrict__ sse_g,
            int* __restrict__ counts)
{
#pragma clang fp contract(off)
    __shared__ int    hist[K];
    __shared__ double wsum[4];
    const int tid = threadIdx.x;
    for (int i = tid; i < K; i += 256) hist[i] = 0;
    __syncthreads();

    const int n  = blockIdx.x * 256 + tid;
    const int bt = n >> 12;           // (b*16+t)
    const int hw = n & 4095;          // h*64+w
    const size_t base = ((size_t)bt << 18) + (size_t)hw;
    const float* xv = x + base;

    // Load the 64-element vector (coalesced across lanes for each c).
    float f[CDIM];
    #pragma unroll
    for (int c = 0; c < CDIM; ++c) f[c] = xv[(size_t)c << 12];

    // S1 = np pairwise sum of f*f (squares rounded first)
    float r[8];
    #pragma unroll
    for (int j = 0; j < 8; ++j) r[j] = f[j] * f[j];
    #pragma unroll
    for (int i = 8; i < CDIM; i += 8)
        #pragma unroll
        for (int j = 0; j < 8; ++j) r[j] += f[i + j] * f[i + j];
    const float S1 = ((r[0] + r[1]) + (r[2] + r[3])) + ((r[4] + r[5]) + (r[6] + r[7]));

    // Fence: never executes, but the compiler cannot prove n != -1, so x is
    // potentially clobbered -> re-loading f[] from memory below is illegal.
    if (n == -1) const_cast<float*>(x)[0] = 0.f;

    float best  = 3.4e38f;
    int   bestk = 0;

    for (int k8 = 0; k8 < K; k8 += 8) {
        const float* eb = cb + (k8 << 6);
        float g0 = 0.f, g1 = 0.f, g2 = 0.f, g3 = 0.f;
        float g4 = 0.f, g5 = 0.f, g6 = 0.f, g7 = 0.f;
        #pragma unroll
        for (int c = 0; c < CDIM; ++c) {
            const float fc = f[c];
            const float e0 = eb[0 * 64 + c], e1 = eb[1 * 64 + c];
            const float e2 = eb[2 * 64 + c], e3 = eb[3 * 64 + c];
            const float e4 = eb[4 * 64 + c], e5 = eb[5 * 64 + c];
            const float e6 = eb[6 * 64 + c], e7 = eb[7 * 64 + c];
            // One un-duplicable block: fc materialized once for 8 fmas.
            asm("v_fmac_f32 %0, %9, %8\n\t"
                "v_fmac_f32 %1, %10, %8\n\t"
                "v_fmac_f32 %2, %11, %8\n\t"
                "v_fmac_f32 %3, %12, %8\n\t"
                "v_fmac_f32 %4, %13, %8\n\t"
                "v_fmac_f32 %5, %14, %8\n\t"
                "v_fmac_f32 %6, %15, %8\n\t"
                "v_fmac_f32 %7, %16, %8"
                : "+v"(g0), "+v"(g1), "+v"(g2), "+v"(g3),
                  "+v"(g4), "+v"(g5), "+v"(g6), "+v"(g7)
                : "v"(fc),
                  "s"(e0), "s"(e1), "s"(e2), "s"(e3),
                  "s"(e4), "s"(e5), "s"(e6), "s"(e7));
        }
        // D = (S1 - 2*G) + S2 (2*G exact; both adds round at magnitude ~64,
        // exactly like numpy's broadcast expression); first-min, ascending k.
        const float D0 = (S1 - 2.f * g0) + S2g[k8 + 0];
        const float D1 = (S1 - 2.f * g1) + S2g[k8 + 1];
        const float D2 = (S1 - 2.f * g2) + S2g[k8 + 2];
        const float D3 = (S1 - 2.f * g3) + S2g[k8 + 3];
        const float D4 = (S1 - 2.f * g4) + S2g[k8 + 4];
        const float D5 = (S1 - 2.f * g5) + S2g[k8 + 5];
        const float D6 = (S1 - 2.f * g6) + S2g[k8 + 6];
        const float D7 = (S1 - 2.f * g7) + S2g[k8 + 7];
        if (D0 < best) { best = D0; bestk = k8 + 0; }
        if (D1 < best) { best = D1; bestk = k8 + 1; }
        if (D2 < best) { best = D2; bestk = k8 + 2; }
        if (D3 < best) { best = D3; bestk = k8 + 3; }
        if (D4 < best) { best = D4; bestk = k8 + 4; }
        if (D5 < best) { best = D5; bestk = k8 + 5; }
        if (D6 < best) { best = D6; bestk = k8 + 6; }
        if (D7 < best) { best = D7; bestk = k8 + 7; }
    }

    // ---------------- epilogue ----------------
    atomicAdd(&hist[bestk], 1);
    outidx[n] = (float)bestk;

    const float4* e4v = (const float4*)(cb + (bestk << 6));
    double acc = 0.0;
    #pragma unroll
    for (int c4 = 0; c4 < 16; ++c4) {
        float4 e = e4v[c4];
        const int c = c4 * 4;
        float d0 = e.x - f[c + 0];
        float d1 = e.y - f[c + 1];
        float d2 = e.z - f[c + 2];
        float d3 = e.w - f[c + 3];
        outq[base + ((size_t)(c + 0) << 12)] = e.x;
        outq[base + ((size_t)(c + 1) << 12)] = e.y;
        outq[base + ((size_t)(c + 2) << 12)] = e.z;
        outq[base + ((size_t)(c + 3) << 12)] = e.w;
        acc += (double)d0 * d0 + (double)d1 * d1 + (double)d2 * d2 + (double)d3 * d3;
    }

    double v = acc;
    #pragma unroll
    for (int off = 32; off; off >>= 1) v += __shfl_down(v, off, 64);
    if ((tid & 63) == 0) wsum[tid >> 6] = v;
    __syncthreads();
    if (tid == 0) atomicAdd(sse_g, wsum[0] + wsum[1] + wsum[2] + wsum[3]);

    for (int i = tid; i < K; i += 256) {
        int h = hist[i];
        if (h) atomicAdd(&counts[i], h);
    }
}

// ---------------------------------------------------------------------------
// Scalars: vq_loss = 1.25 * SSE / NELEM; entropy in bits from counts.
__global__ void k_final(const double* __restrict__ sse_g, const int* __restrict__ counts,
                        float* __restrict__ out_scalars)
{
    __shared__ double part[8];
    const int t = threadIdx.x;  // 512 threads
    int c = counts[t];
    double p = (double)c / (double)NVEC;
    double h = (c > 0) ? (-p * log2(p)) : 0.0;
    #pragma unroll
    for (int off = 32; off; off >>= 1) h += __shfl_down(h, off, 64);
    if ((t & 63) == 0) part[t >> 6] = h;
    __syncthreads();
    if (t == 0) {
        double H = 0.0;
        #pragma unroll
        for (int i = 0; i < 8; ++i) H += part[i];
        out_scalars[0] = (float)(1.25 * (*sse_g) / (double)NELEM);
        out_scalars[1] = (float)H;
    }
}

// ---------------------------------------------------------------------------
extern "C" void kernel_launch(void* const* d_in, const int* in_sizes, int n_in,
                              void* d_out, int out_size, void* d_ws, size_t ws_size,
                              hipStream_t stream)
{
    const float* x  = (const float*)d_in[0];
    const float* cb = (const float*)d_in[1];

    char* ws = (char*)d_ws;
    double* sse    = (double*)(ws + OFF_SSE);
    int*    counts = (int*)   (ws + OFF_COUNTS);
    float*  S2     = (float*) (ws + OFF_S2);

    float* outq   = (float*)d_out;
    float* outidx = outq + NELEM;
    float* outsc  = outidx + NVEC;

    // zero sse + counts (ws is poisoned 0xAA before every launch)
    hipMemsetAsync(d_ws, 0, OFF_S2, stream);

    k_prep <<<1, 512, 0, stream>>>(cb, S2);
    k_main <<<NVEC / 256, 256, 0, stream>>>(x, cb, S2, outq, outidx, sse, counts);
    k_final<<<1, 512, 0, stream>>>(sse, counts, outsc);
}